// Round 1
// baseline (577.533 us; speedup 1.0000x reference)
//
#include <hip/hip_runtime.h>
#include <hip/hip_bf16.h>
#include <stdint.h>

#define H 128
#define NNODES 100000
#define NEDGE 500000
#define NB 8  // nodes per block in precompute

// ws layout:
//   [0, 131072)                      : w1T fp32, w1t[j*256 + k] = w1[k*128 + j]
//   [131072, +25.6MB) x4             : T_ps, T_pd, T_os, T_od  bf16 [100000][128]
#define W1T_BYTES 131072
#define TBL_ELEMS (NNODES * H)
#define WS_NEEDED ((size_t)W1T_BYTES + 4ULL * TBL_ELEMS * 2ULL)

__device__ __forceinline__ void bf2_to_f(uint32_t u, float& lo, float& hi) {
    union { uint32_t i; float f; } a, b;
    a.i = u << 16;
    b.i = u & 0xffff0000u;
    lo = a.f;
    hi = b.f;
}

__global__ __launch_bounds__(256) void prep_w1t(const float* __restrict__ w1,
                                                float* __restrict__ w1t) {
    int i = blockIdx.x * 256 + threadIdx.x;  // 0..32767
    int j = i >> 8;    // 0..127 output channel
    int k = i & 255;   // 0..255 input channel
    w1t[i] = w1[k * H + j];
}

__global__ __launch_bounds__(128) void precompute_tables(
    const float* __restrict__ zp, const float* __restrict__ zo,
    const float* __restrict__ w1t, const float* __restrict__ b1,
    __hip_bfloat16* __restrict__ t_ps, __hip_bfloat16* __restrict__ t_pd,
    __hip_bfloat16* __restrict__ t_os, __hip_bfloat16* __restrict__ t_od) {
    const int j = threadIdx.x;            // output channel 0..127
    const int node0 = blockIdx.x * NB;

    float acc_ps[NB], acc_pd[NB], acc_os[NB], acc_od[NB];
#pragma unroll
    for (int n = 0; n < NB; ++n) {
        acc_ps[n] = 0.f; acc_pd[n] = 0.f; acc_os[n] = 0.f; acc_od[n] = 0.f;
    }

    const float4* wt_ptr = (const float4*)(w1t + j * 2 * H);      // k = 0..127
    const float4* wb_ptr = (const float4*)(w1t + j * 2 * H + H);  // k = 128..255

    for (int kq = 0; kq < H / 4; ++kq) {
        const float4 wt = wt_ptr[kq];
        const float4 wb = wb_ptr[kq];
#pragma unroll
        for (int n = 0; n < NB; ++n) {
            // block-uniform addresses -> scalar (or broadcast) loads
            const float4 zp4 = *(const float4*)(zp + (node0 + n) * H + kq * 4);
            const float4 zo4 = *(const float4*)(zo + (node0 + n) * H + kq * 4);
            acc_ps[n] += zp4.x * wt.x; acc_ps[n] += zp4.y * wt.y;
            acc_ps[n] += zp4.z * wt.z; acc_ps[n] += zp4.w * wt.w;
            acc_pd[n] += zp4.x * wb.x; acc_pd[n] += zp4.y * wb.y;
            acc_pd[n] += zp4.z * wb.z; acc_pd[n] += zp4.w * wb.w;
            acc_os[n] += zo4.x * wt.x; acc_os[n] += zo4.y * wt.y;
            acc_os[n] += zo4.z * wt.z; acc_os[n] += zo4.w * wt.w;
            acc_od[n] += zo4.x * wb.x; acc_od[n] += zo4.y * wb.y;
            acc_od[n] += zo4.z * wb.z; acc_od[n] += zo4.w * wb.w;
        }
    }

    const float bias = b1[j];
#pragma unroll
    for (int n = 0; n < NB; ++n) {
        const int row = (node0 + n) * H + j;
        t_ps[row] = __float2bfloat16(acc_ps[n]);
        t_pd[row] = __float2bfloat16(acc_pd[n] + bias);
        t_os[row] = __float2bfloat16(acc_os[n]);
        t_od[row] = __float2bfloat16(acc_od[n] + bias);
    }
}

// 16 lanes per edge; each lane handles 8 channels (16B bf16 loads).
__global__ __launch_bounds__(256) void edge_kernel(
    const __hip_bfloat16* __restrict__ t_ps, const __hip_bfloat16* __restrict__ t_pd,
    const __hip_bfloat16* __restrict__ t_os, const __hip_bfloat16* __restrict__ t_od,
    const int* __restrict__ ptnp, const int* __restrict__ nptp,
    const int* __restrict__ nptnp,
    const float* __restrict__ w2, const float* __restrict__ b2,
    float* __restrict__ out) {
    const int tid = blockIdx.x * 256 + threadIdx.x;
    const int g = tid >> 4;        // edge id 0..3E-1
    const int lane = tid & 15;

    const __hip_bfloat16 *src_tbl, *dst_tbl;
    int si, di;
    if (g < NEDGE) {
        si = ptnp[g]; di = ptnp[NEDGE + g];
        src_tbl = t_ps; dst_tbl = t_od;
    } else if (g < 2 * NEDGE) {
        const int e = g - NEDGE;
        si = nptp[e]; di = nptp[NEDGE + e];
        src_tbl = t_os; dst_tbl = t_pd;
    } else {
        const int e = g - 2 * NEDGE;
        si = nptnp[e]; di = nptnp[NEDGE + e];
        src_tbl = t_os; dst_tbl = t_od;
    }

    const uint4 s4 = *(const uint4*)(src_tbl + si * H + lane * 8);
    const uint4 d4 = *(const uint4*)(dst_tbl + di * H + lane * 8);
    const float4 w2a = *(const float4*)(w2 + lane * 8);
    const float4 w2b = *(const float4*)(w2 + lane * 8 + 4);

    float s0, s1, d0, d1;
    float sum = 0.f;
    bf2_to_f(s4.x, s0, s1); bf2_to_f(d4.x, d0, d1);
    sum = fmaf(fmaxf(s0 + d0, 0.f), w2a.x, sum);
    sum = fmaf(fmaxf(s1 + d1, 0.f), w2a.y, sum);
    bf2_to_f(s4.y, s0, s1); bf2_to_f(d4.y, d0, d1);
    sum = fmaf(fmaxf(s0 + d0, 0.f), w2a.z, sum);
    sum = fmaf(fmaxf(s1 + d1, 0.f), w2a.w, sum);
    bf2_to_f(s4.z, s0, s1); bf2_to_f(d4.z, d0, d1);
    sum = fmaf(fmaxf(s0 + d0, 0.f), w2b.x, sum);
    sum = fmaf(fmaxf(s1 + d1, 0.f), w2b.y, sum);
    bf2_to_f(s4.w, s0, s1); bf2_to_f(d4.w, d0, d1);
    sum = fmaf(fmaxf(s0 + d0, 0.f), w2b.z, sum);
    sum = fmaf(fmaxf(s1 + d1, 0.f), w2b.w, sum);

    sum += __shfl_down(sum, 8, 16);
    sum += __shfl_down(sum, 4, 16);
    sum += __shfl_down(sum, 2, 16);
    sum += __shfl_down(sum, 1, 16);
    if (lane == 0) out[g] = sum + b2[0];
}

// Fallback (only if ws_size is too small): direct per-edge compute, fp32.
__global__ __launch_bounds__(128) void edge_direct(
    const float* __restrict__ zp, const float* __restrict__ zo,
    const int* __restrict__ ptnp, const int* __restrict__ nptp,
    const int* __restrict__ nptnp,
    const float* __restrict__ w1, const float* __restrict__ b1,
    const float* __restrict__ w2, const float* __restrict__ b2,
    float* __restrict__ out) {
    const int g = blockIdx.x;
    const int j = threadIdx.x;

    const float *src, *dst;
    int si, di;
    if (g < NEDGE) {
        si = ptnp[g]; di = ptnp[NEDGE + g]; src = zp; dst = zo;
    } else if (g < 2 * NEDGE) {
        const int e = g - NEDGE;
        si = nptp[e]; di = nptp[NEDGE + e]; src = zo; dst = zp;
    } else {
        const int e = g - 2 * NEDGE;
        si = nptnp[e]; di = nptnp[NEDGE + e]; src = zo; dst = zo;
    }
    const float* zs = src + si * H;
    const float* zd = dst + di * H;

    float acc = b1[j];
    for (int k = 0; k < H; ++k) acc = fmaf(zs[k], w1[k * H + j], acc);
    for (int k = 0; k < H; ++k) acc = fmaf(zd[k], w1[(H + k) * H + j], acc);
    float v = fmaxf(acc, 0.f) * w2[j];

    for (int off = 32; off > 0; off >>= 1) v += __shfl_down(v, off, 64);
    __shared__ float parts[2];
    if ((j & 63) == 0) parts[j >> 6] = v;
    __syncthreads();
    if (j == 0) out[g] = parts[0] + parts[1] + b2[0];
}

extern "C" void kernel_launch(void* const* d_in, const int* in_sizes, int n_in,
                              void* d_out, int out_size, void* d_ws, size_t ws_size,
                              hipStream_t stream) {
    const float* zp    = (const float*)d_in[0];
    const float* zo    = (const float*)d_in[1];
    const int*   ptnp  = (const int*)d_in[2];
    const int*   nptp  = (const int*)d_in[3];
    const int*   nptnp = (const int*)d_in[4];
    const float* w1    = (const float*)d_in[5];
    const float* b1    = (const float*)d_in[6];
    const float* w2    = (const float*)d_in[7];
    const float* b2    = (const float*)d_in[8];
    float* out = (float*)d_out;

    if (ws_size < WS_NEEDED) {
        // Workspace too small for table path: slow-but-correct direct kernel.
        edge_direct<<<3 * NEDGE, 128, 0, stream>>>(zp, zo, ptnp, nptp, nptnp,
                                                   w1, b1, w2, b2, out);
        return;
    }

    char* ws = (char*)d_ws;
    float* w1t = (float*)ws;
    __hip_bfloat16* t_ps = (__hip_bfloat16*)(ws + W1T_BYTES);
    __hip_bfloat16* t_pd = t_ps + TBL_ELEMS;
    __hip_bfloat16* t_os = t_pd + TBL_ELEMS;
    __hip_bfloat16* t_od = t_os + TBL_ELEMS;

    prep_w1t<<<128, 256, 0, stream>>>(w1, w1t);
    precompute_tables<<<NNODES / NB, 128, 0, stream>>>(zp, zo, w1t, b1,
                                                       t_ps, t_pd, t_os, t_od);
    const int total_threads = 3 * NEDGE * 16;
    edge_kernel<<<total_threads / 256, 256, 0, stream>>>(t_ps, t_pd, t_os, t_od,
                                                         ptnp, nptp, nptnp,
                                                         w2, b2, out);
}

// Round 2
// 277.235 us; speedup vs baseline: 2.0832x; 2.0832x over previous
//
#include <hip/hip_runtime.h>
#include <hip/hip_bf16.h>
#include <stdint.h>

#define H 128
#define NNODES 100000
#define NEDGE 500000
#define MT 32  // node rows per GEMM block

// ws layout:
//   [0, 65536)        : Bsw  bf16, fragment-swizzled w1 (16 kb-groups x 256 cols x 8)
//   [65536, +25.6MB)x4: T_ps, T_pd, T_os, T_od  bf16 [100000][128]
#define BSW_BYTES 65536
#define TBL_ELEMS (NNODES * H)
#define WS_NEEDED ((size_t)BSW_BYTES + 4ULL * TBL_ELEMS * 2ULL)

typedef __bf16 bf16x8 __attribute__((ext_vector_type(8)));
typedef float f32x4 __attribute__((ext_vector_type(4)));

union frag_cast { uint4 u; bf16x8 b; };

__device__ __forceinline__ ushort f2bf(float f) {
    __hip_bfloat16 h = __float2bfloat16(f);
    return *(ushort*)&h;
}

__device__ __forceinline__ void bf2_to_f(uint32_t u, float& lo, float& hi) {
    union { uint32_t i; float f; } a, b;
    a.i = u << 16;
    b.i = u & 0xffff0000u;
    lo = a.f;
    hi = b.f;
}

// Build fragment-swizzled bf16 B from w1.
// Bsw element i: j=i&7, n=(i>>3)&255, kb=i>>11; k=kb*8+j;
// B[k][n] = (n<128) ? w1[k][n] : w1[128+k][n-128]
__global__ __launch_bounds__(256) void prep_bsw(const float* __restrict__ w1,
                                                ushort* __restrict__ bsw) {
    int i = blockIdx.x * 256 + threadIdx.x;  // 0..32767
    int j = i & 7;
    int n = (i >> 3) & 255;
    int kb = i >> 11;
    int k = kb * 8 + j;
    int r = (n < 128) ? k : (128 + k);
    int c = n & 127;
    bsw[i] = f2bf(w1[r * H + c]);
}

// GEMM: [32 rows, K=128] x [128, 256] -> bf16 tables, one tile per block.
// blockIdx.y: 0 = zp -> (t_ps|t_pd), 1 = zo -> (t_os|t_od)
__global__ __launch_bounds__(256) void gemm_tables(
    const float* __restrict__ zp, const float* __restrict__ zo,
    const ushort* __restrict__ bsw, const float* __restrict__ b1,
    ushort* __restrict__ t_ps, ushort* __restrict__ t_pd,
    ushort* __restrict__ t_os, ushort* __restrict__ t_od) {
    __shared__ ushort lds[32 * 280];  // A phase uses 32*128; epilogue 32*280

    const int t = threadIdx.x;
    const int node0 = blockIdx.x * MT;
    const int zsel = blockIdx.y;
    const float* __restrict__ z = zsel ? ((const float*)zo) : ((const float*)zp);

    // ---- Stage A: 32 rows x 128 k, fp32 -> bf16 into LDS (XOR-swizzled kb) ----
#pragma unroll
    for (int c = 0; c < 4; ++c) {
        const int flat = (c * 256 + t) * 4;  // 0..4095, contiguous coalesced
        const float4 v = *(const float4*)(z + node0 * H + flat);
        const int row = flat >> 7;
        const int col = flat & 127;
        const int kb = col >> 3;
        const int sw = kb ^ (row & 15);
        ushort4 o;
        o.x = f2bf(v.x); o.y = f2bf(v.y); o.z = f2bf(v.z); o.w = f2bf(v.w);
        *(ushort4*)(lds + row * 128 + sw * 8 + (col & 7)) = o;
    }

    const int wave = t >> 6;
    const int lane = t & 63;
    const int l15 = lane & 15;
    const int quad = lane >> 4;
    const int n0 = wave * 64;  // this wave's first output col

    // ---- Preload B fragments (16 x 16B loads, L2-hot) ----
    frag_cast bfr[4][4];  // [s][nt]
#pragma unroll
    for (int s = 0; s < 4; ++s) {
#pragma unroll
        for (int nt = 0; nt < 4; ++nt) {
            const int kb_idx = s * 4 + quad;
            const int n = n0 + nt * 16 + l15;
            bfr[s][nt].u = *(const uint4*)(bsw + (kb_idx * 256 + n) * 8);
        }
    }

    f32x4 acc[2][4];
#pragma unroll
    for (int mt = 0; mt < 2; ++mt)
#pragma unroll
        for (int nt = 0; nt < 4; ++nt)
            acc[mt][nt] = (f32x4){0.f, 0.f, 0.f, 0.f};

    __syncthreads();

    // ---- MFMA main: K=128 fully unrolled ----
#pragma unroll
    for (int s = 0; s < 4; ++s) {
        frag_cast a[2];
#pragma unroll
        for (int mt = 0; mt < 2; ++mt) {
            const int row = mt * 16 + l15;
            const int kb = s * 4 + quad;
            const int sw = kb ^ l15;
            a[mt].u = *(const uint4*)(lds + row * 128 + sw * 8);
        }
#pragma unroll
        for (int mt = 0; mt < 2; ++mt)
#pragma unroll
            for (int nt = 0; nt < 4; ++nt)
                acc[mt][nt] = __builtin_amdgcn_mfma_f32_16x16x32_bf16(
                    a[mt].b, bfr[s][nt].b, acc[mt][nt], 0, 0, 0);
    }

    __syncthreads();  // done reading A-LDS; reuse buffer for epilogue

    // ---- Bias (cols >= 128 only; wave-uniform) ----
    float bias[4] = {0.f, 0.f, 0.f, 0.f};
    if (wave >= 2) {
#pragma unroll
        for (int nt = 0; nt < 4; ++nt)
            bias[nt] = b1[(n0 - 128) + nt * 16 + l15];
    }

    // ---- Epilogue: acc -> LDS [32][280] bf16 (D: col=l15, row=quad*4+reg) ----
#pragma unroll
    for (int mt = 0; mt < 2; ++mt)
#pragma unroll
        for (int nt = 0; nt < 4; ++nt)
#pragma unroll
            for (int r = 0; r < 4; ++r) {
                const int row = mt * 16 + quad * 4 + r;
                const int col = n0 + nt * 16 + l15;
                lds[row * 280 + col] = f2bf(acc[mt][nt][r] + bias[nt]);
            }
    __syncthreads();

    // ---- Coalesced store: cols 0..127 -> t_s, 128..255 -> t_d ----
    const int table = t >> 7;   // 0 = s-table, 1 = d-table
    const int tt = t & 127;
    const int row = tt >> 2;
    const int cbase = (tt & 3) * 32;
    ushort* __restrict__ dst =
        zsel ? (table ? t_od : t_os) : (table ? t_pd : t_ps);
    const size_t obase = (size_t)(node0 + row) * H + cbase;
    const int lbase = row * 280 + table * 128 + cbase;
#pragma unroll
    for (int q = 0; q < 4; ++q) {
        *(uint4*)(dst + obase + q * 8) = *(const uint4*)(lds + lbase + q * 8);
    }
}

// 16 lanes per edge; each lane handles 8 channels (16B bf16 loads).
__global__ __launch_bounds__(256) void edge_kernel(
    const __hip_bfloat16* __restrict__ t_ps, const __hip_bfloat16* __restrict__ t_pd,
    const __hip_bfloat16* __restrict__ t_os, const __hip_bfloat16* __restrict__ t_od,
    const int* __restrict__ ptnp, const int* __restrict__ nptp,
    const int* __restrict__ nptnp,
    const float* __restrict__ w2, const float* __restrict__ b2,
    float* __restrict__ out) {
    const int tid = blockIdx.x * 256 + threadIdx.x;
    const int g = tid >> 4;        // edge id 0..3E-1
    const int lane = tid & 15;

    const __hip_bfloat16 *src_tbl, *dst_tbl;
    int si, di;
    if (g < NEDGE) {
        si = ptnp[g]; di = ptnp[NEDGE + g];
        src_tbl = t_ps; dst_tbl = t_od;
    } else if (g < 2 * NEDGE) {
        const int e = g - NEDGE;
        si = nptp[e]; di = nptp[NEDGE + e];
        src_tbl = t_os; dst_tbl = t_pd;
    } else {
        const int e = g - 2 * NEDGE;
        si = nptnp[e]; di = nptnp[NEDGE + e];
        src_tbl = t_os; dst_tbl = t_od;
    }

    const uint4 s4 = *(const uint4*)(src_tbl + si * H + lane * 8);
    const uint4 d4 = *(const uint4*)(dst_tbl + di * H + lane * 8);
    const float4 w2a = *(const float4*)(w2 + lane * 8);
    const float4 w2b = *(const float4*)(w2 + lane * 8 + 4);

    float s0, s1, d0, d1;
    float sum = 0.f;
    bf2_to_f(s4.x, s0, s1); bf2_to_f(d4.x, d0, d1);
    sum = fmaf(fmaxf(s0 + d0, 0.f), w2a.x, sum);
    sum = fmaf(fmaxf(s1 + d1, 0.f), w2a.y, sum);
    bf2_to_f(s4.y, s0, s1); bf2_to_f(d4.y, d0, d1);
    sum = fmaf(fmaxf(s0 + d0, 0.f), w2a.z, sum);
    sum = fmaf(fmaxf(s1 + d1, 0.f), w2a.w, sum);
    bf2_to_f(s4.z, s0, s1); bf2_to_f(d4.z, d0, d1);
    sum = fmaf(fmaxf(s0 + d0, 0.f), w2b.x, sum);
    sum = fmaf(fmaxf(s1 + d1, 0.f), w2b.y, sum);
    bf2_to_f(s4.w, s0, s1); bf2_to_f(d4.w, d0, d1);
    sum = fmaf(fmaxf(s0 + d0, 0.f), w2b.z, sum);
    sum = fmaf(fmaxf(s1 + d1, 0.f), w2b.w, sum);

    sum += __shfl_down(sum, 8, 16);
    sum += __shfl_down(sum, 4, 16);
    sum += __shfl_down(sum, 2, 16);
    sum += __shfl_down(sum, 1, 16);
    if (lane == 0) out[g] = sum + b2[0];
}

// Fallback (only if ws_size is too small): direct per-edge compute, fp32.
__global__ __launch_bounds__(128) void edge_direct(
    const float* __restrict__ zp, const float* __restrict__ zo,
    const int* __restrict__ ptnp, const int* __restrict__ nptp,
    const int* __restrict__ nptnp,
    const float* __restrict__ w1, const float* __restrict__ b1,
    const float* __restrict__ w2, const float* __restrict__ b2,
    float* __restrict__ out) {
    const int g = blockIdx.x;
    const int j = threadIdx.x;

    const float *src, *dst;
    int si, di;
    if (g < NEDGE) {
        si = ptnp[g]; di = ptnp[NEDGE + g]; src = zp; dst = zo;
    } else if (g < 2 * NEDGE) {
        const int e = g - NEDGE;
        si = nptp[e]; di = nptp[NEDGE + e]; src = zo; dst = zp;
    } else {
        const int e = g - 2 * NEDGE;
        si = nptnp[e]; di = nptnp[NEDGE + e]; src = zo; dst = zo;
    }
    const float* zs = src + si * H;
    const float* zd = dst + di * H;

    float acc = b1[j];
    for (int k = 0; k < H; ++k) acc = fmaf(zs[k], w1[k * H + j], acc);
    for (int k = 0; k < H; ++k) acc = fmaf(zd[k], w1[(H + k) * H + j], acc);
    float v = fmaxf(acc, 0.f) * w2[j];

    for (int off = 32; off > 0; off >>= 1) v += __shfl_down(v, off, 64);
    __shared__ float parts[2];
    if ((j & 63) == 0) parts[j >> 6] = v;
    __syncthreads();
    if (j == 0) out[g] = parts[0] + parts[1] + b2[0];
}

extern "C" void kernel_launch(void* const* d_in, const int* in_sizes, int n_in,
                              void* d_out, int out_size, void* d_ws, size_t ws_size,
                              hipStream_t stream) {
    const float* zp    = (const float*)d_in[0];
    const float* zo    = (const float*)d_in[1];
    const int*   ptnp  = (const int*)d_in[2];
    const int*   nptp  = (const int*)d_in[3];
    const int*   nptnp = (const int*)d_in[4];
    const float* w1    = (const float*)d_in[5];
    const float* b1    = (const float*)d_in[6];
    const float* w2    = (const float*)d_in[7];
    const float* b2    = (const float*)d_in[8];
    float* out = (float*)d_out;

    if (ws_size < WS_NEEDED) {
        edge_direct<<<3 * NEDGE, 128, 0, stream>>>(zp, zo, ptnp, nptp, nptnp,
                                                   w1, b1, w2, b2, out);
        return;
    }

    char* ws = (char*)d_ws;
    ushort* bsw = (ushort*)ws;
    ushort* t_ps = (ushort*)(ws + BSW_BYTES);
    ushort* t_pd = t_ps + TBL_ELEMS;
    ushort* t_os = t_pd + TBL_ELEMS;
    ushort* t_od = t_os + TBL_ELEMS;

    prep_bsw<<<128, 256, 0, stream>>>(w1, bsw);
    gemm_tables<<<dim3(NNODES / MT, 2), 256, 0, stream>>>(
        zp, zo, bsw, b1, t_ps, t_pd, t_os, t_od);

    const int total_threads = 3 * NEDGE * 16;
    edge_kernel<<<total_threads / 256, 256, 0, stream>>>(
        (const __hip_bfloat16*)t_ps, (const __hip_bfloat16*)t_pd,
        (const __hip_bfloat16*)t_os, (const __hip_bfloat16*)t_od,
        ptnp, nptp, nptnp, w2, b2, out);
}